// Round 2
// baseline (831.021 us; speedup 1.0000x reference)
//
#include <hip/hip_runtime.h>

#define GI  1220          // g_i feature dim
#define KP  1280          // K padded to 40 * 32
#define BK  128           // K-chunk staged in LDS
#define NCH (KP / BK)     // 10 chunks
#define NP  192           // hidden dim padded 150 -> 192 (12 * 16)
#define ABW 320           // AB row: A[0:160) | B[160:320), cols >=150 zero

typedef __bf16        bf16x8 __attribute__((ext_vector_type(8)));
typedef float         f32x4  __attribute__((ext_vector_type(4)));
typedef unsigned int  u32x4  __attribute__((ext_vector_type(4)));
typedef unsigned int  u32x2  __attribute__((ext_vector_type(2)));

__device__ __forceinline__ unsigned short f2bf(float f) {
  __bf16 h = (__bf16)f;
  return __builtin_bit_cast(unsigned short, h);
}
__device__ __forceinline__ float bf2f(unsigned short u) {
  return (float)__builtin_bit_cast(__bf16, u);
}
__device__ __forceinline__ unsigned int pk2(float a, float b) {
  return (unsigned int)f2bf(a) | ((unsigned int)f2bf(b) << 16);
}
// packed bf16x2 product: a,b each hold two bf16; returns two bf16 products
__device__ __forceinline__ unsigned int mulbf2(unsigned int a, unsigned int b) {
  float xl = __builtin_bit_cast(float, a << 16);
  float xh = __builtin_bit_cast(float, a & 0xffff0000u);
  float yl = __builtin_bit_cast(float, b << 16);
  float yh = __builtin_bit_cast(float, b & 0xffff0000u);
  return pk2(xl * yl, xh * yh);
}

// ---------------------------------------------------------------------------
// prep: build bf16 transposed weight layouts + fp32 proj tables in ws.
// ---------------------------------------------------------------------------
__global__ void prep_kernel(const float* __restrict__ W1, const float* __restrict__ W2,
                            const float* __restrict__ b1,
                            const float* __restrict__ de, const float* __restrict__ ge,
                            const float* __restrict__ se,
                            unsigned short* __restrict__ W1ab_t,
                            unsigned short* __restrict__ W1c_t,
                            unsigned short* __restrict__ W2_t,
                            float* __restrict__ projs) {
  int idx = blockIdx.x * 256 + threadIdx.x;
  const int R1 = ABW * KP, R2 = NP * KP, R3 = NP * NP, R4 = 20 * NP;
  if (idx < R1) {
    int n = idx / KP, k = idx % KP;
    float v = 0.f;
    if (k < GI) {
      if (n < 150)                 v = W1[k * 150 + n];
      else if (n >= 160 && n < 310) v = W1[(GI + k) * 150 + (n - 160)];
    }
    W1ab_t[idx] = f2bf(v);
    return;
  }
  idx -= R1;
  if (idx < R2) {
    int n = idx / KP, k = idx % KP;
    float v = (k < GI && n < 150) ? W1[(2 * GI + k) * 150 + n] : 0.f;
    W1c_t[idx] = f2bf(v);
    return;
  }
  idx -= R2;
  if (idx < R3) {
    int n = idx / NP, k = idx % NP;
    float v = (n < 150 && k < 150) ? W2[k * 150 + n] : 0.f;
    W2_t[idx] = f2bf(v);
    return;
  }
  idx -= R3;
  if (idx < R4) {
    int r = idx / NP, n = idx % NP;
    float v = 0.f;
    if (n < 150) {
      if (r < 9) {
        v = b1[n];
        for (int t = 0; t < 20; ++t) v += de[r * 20 + t] * W1[(3660 + t) * 150 + n];
      } else if (r < 17) {
        int q = r - 9;
        for (int t = 0; t < 20; ++t) v += ge[q * 20 + t] * W1[(3680 + t) * 150 + n];
      } else {
        int q = r - 17;
        for (int t = 0; t < 20; ++t) v += se[q * 20 + t] * W1[(3700 + t) * 150 + n];
      }
    }
    projs[idx] = v;
  }
}

// ---------------------------------------------------------------------------
// ab_kernel: AB[m] = [(G@W1a)[m] | (G@W1b)[m]] bf16; also emits g_pad (bf16,
// zero-padded to KP) if gpad != nullptr — free: it already stages exactly
// this data per chunk.
// ---------------------------------------------------------------------------
__global__ __launch_bounds__(256, 3)
void ab_kernel(const float* __restrict__ g, const unsigned short* __restrict__ W1ab_t,
               unsigned short* __restrict__ AB, unsigned short* __restrict__ gpad,
               int N) {
  __shared__ __attribute__((aligned(16))) unsigned short sX[64 * 136];
  const int t = threadIdx.x;
  const int m0 = blockIdx.x * 64;
  const int w = t >> 6, lane = t & 63, quad = lane >> 4, lm = lane & 15;

  f32x4 acc[4][5];
#pragma unroll
  for (int a = 0; a < 4; ++a)
#pragma unroll
    for (int b = 0; b < 5; ++b) { acc[a][b].x = 0.f; acc[a][b].y = 0.f; acc[a][b].z = 0.f; acc[a][b].w = 0.f; }

  const int r = t >> 2, s = t & 3;
  int row = m0 + r; if (row >= N) row = N - 1;
  const float* gr = g + (long)row * GI;

  for (int c = 0; c < NCH; ++c) {
    __syncthreads();
#pragma unroll
    for (int i = 0; i < 8; ++i) {
      int k = c * BK + i * 16 + s * 4;
      u32x2 pk; pk.x = 0u; pk.y = 0u;
      if (k < GI) {
        f32x4 x = *(const f32x4*)(gr + k);
        pk.x = pk2(x.x, x.y);
        pk.y = pk2(x.z, x.w);
      }
      *(u32x2*)&sX[r * 136 + i * 16 + s * 4] = pk;
      if (gpad) *(u32x2*)(gpad + (long)row * KP + k) = pk;   // dup rows write same data: benign
    }
    __syncthreads();
#pragma unroll
    for (int kk = 0; kk < 4; ++kk) {
      bf16x8 af[4];
#pragma unroll
      for (int mi = 0; mi < 4; ++mi)
        af[mi] = __builtin_bit_cast(bf16x8, *(const u32x4*)&sX[(mi * 16 + lm) * 136 + kk * 32 + quad * 8]);
#pragma unroll
      for (int tl = 0; tl < 5; ++tl) {
        int n = (w * 5 + tl) * 16 + lm;
        bf16x8 bfr = __builtin_bit_cast(bf16x8, *(const u32x4*)(W1ab_t + n * KP + c * BK + kk * 32 + quad * 8));
#pragma unroll
        for (int mi = 0; mi < 4; ++mi)
          acc[mi][tl] = __builtin_amdgcn_mfma_f32_16x16x32_bf16(af[mi], bfr, acc[mi][tl], 0, 0, 0);
      }
    }
  }
#pragma unroll
  for (int mi = 0; mi < 4; ++mi)
#pragma unroll
    for (int reg = 0; reg < 4; ++reg) {
      int m = m0 + mi * 16 + quad * 4 + reg;
      if (m < N) {
#pragma unroll
        for (int tl = 0; tl < 5; ++tl) {
          int n = (w * 5 + tl) * 16 + lm;
          AB[(long)m * ABW + n] = f2bf(acc[mi][tl][reg]);
        }
      }
    }
}

// ---------------------------------------------------------------------------
// pair_kernel: fused per 64 pairs, single shared LDS buffer (bias/h1/h2 all
// live in the same (m,n)-owned cells -> 26 KB LDS -> 5 blocks/CU).
// PADG: gather bf16 g_pad (L3-resident, no K-guard) instead of fp32 g.
// ---------------------------------------------------------------------------
template <bool PADG>
__global__ __launch_bounds__(256, 5)
void pair_kernel(const float* __restrict__ g, const unsigned short* __restrict__ gpad,
                 const float* __restrict__ msc,
                 const unsigned short* __restrict__ AB,
                 const unsigned short* __restrict__ W1c_t,
                 const unsigned short* __restrict__ W2_t,
                 const float* __restrict__ projs,
                 const float* __restrict__ b2, const float* __restrict__ W3,
                 const float* __restrict__ b3,
                 const int* __restrict__ mid, const int* __restrict__ aid,
                 const int* __restrict__ did, const int* __restrict__ gid,
                 const int* __restrict__ sid,
                 float* __restrict__ out, int P) {
  __shared__ __attribute__((aligned(16))) unsigned short sX[64 * 200];  // stage(136) / bias->h1->h2 (200)
  __shared__ int sM[64], sA[64], sDGS[64];

  const int t = threadIdx.x;
  const int p0 = blockIdx.x * 64;
  const int w = t >> 6, lane = t & 63, quad = lane >> 4, lm = lane & 15;

  if (t < 64) {
    int p = p0 + t;
    int m_ = 0, a_ = 0, dgs = 0;
    if (p < P) {
      m_ = mid[p]; a_ = aid[p];
      dgs = did[p] | (gid[p] << 4) | (sid[p] << 8);
    }
    sM[t] = m_; sA[t] = a_; sDGS[t] = dgs;
  }
  __syncthreads();

  const int r = t >> 2, s = t & 3;

  // ---- layer 1 bilinear over K = 1280 (zero-padded)
  f32x4 acc[4][3];
#pragma unroll
  for (int a = 0; a < 4; ++a)
#pragma unroll
    for (int b = 0; b < 3; ++b) { acc[a][b].x = 0.f; acc[a][b].y = 0.f; acc[a][b].z = 0.f; acc[a][b].w = 0.f; }

  const float* gm32; const float* ga32;
  const unsigned short* gm16; const unsigned short* ga16;
  if constexpr (PADG) {
    gm16 = gpad + (long)sM[r] * KP;
    ga16 = gpad + (long)sA[r] * KP;
  } else {
    gm32 = g + (long)sM[r] * GI;
    ga32 = g + (long)sA[r] * GI;
  }

  for (int c = 0; c < NCH; ++c) {
    __syncthreads();
    if constexpr (PADG) {
#pragma unroll
      for (int i = 0; i < 4; ++i) {
        int k = c * BK + i * 32 + s * 8;
        u32x4 xx = *(const u32x4*)(gm16 + k);
        u32x4 yy = *(const u32x4*)(ga16 + k);
        u32x4 o;
        o.x = mulbf2(xx.x, yy.x);
        o.y = mulbf2(xx.y, yy.y);
        o.z = mulbf2(xx.z, yy.z);
        o.w = mulbf2(xx.w, yy.w);
        *(u32x4*)&sX[r * 136 + i * 32 + s * 8] = o;
      }
    } else {
#pragma unroll
      for (int i = 0; i < 8; ++i) {
        int k = c * BK + i * 16 + s * 4;
        u32x2 pk; pk.x = 0u; pk.y = 0u;
        if (k < GI) {
          f32x4 x = *(const f32x4*)(gm32 + k);
          f32x4 y = *(const f32x4*)(ga32 + k);
          pk.x = pk2(x.x * y.x, x.y * y.y);
          pk.y = pk2(x.z * y.z, x.w * y.w);
        }
        *(u32x2*)&sX[r * 136 + i * 16 + s * 4] = pk;
      }
    }
    __syncthreads();
#pragma unroll
    for (int kk = 0; kk < 4; ++kk) {
      bf16x8 af[4];
#pragma unroll
      for (int mi = 0; mi < 4; ++mi)
        af[mi] = __builtin_bit_cast(bf16x8, *(const u32x4*)&sX[(mi * 16 + lm) * 136 + kk * 32 + quad * 8]);
#pragma unroll
      for (int tl = 0; tl < 3; ++tl) {
        int n = (w * 3 + tl) * 16 + lm;
        bf16x8 bfr = __builtin_bit_cast(bf16x8, *(const u32x4*)(W1c_t + n * KP + c * BK + kk * 32 + quad * 8));
#pragma unroll
        for (int mi = 0; mi < 4; ++mi)
          acc[mi][tl] = __builtin_amdgcn_mfma_f32_16x16x32_bf16(af[mi], bfr, acc[mi][tl], 0, 0, 0);
      }
    }
  }
  __syncthreads();   // all waves done reading staged X

  // ---- bias tile into sX (stride 200): A[mid] + B[aid] + projs (b1 folded)
  {
    const unsigned short* Ar = AB + (long)sM[r] * ABW;
    const unsigned short* Br = AB + (long)sA[r] * ABW + 160;
    int dgs = sDGS[r];
    const float* dp = projs + (dgs & 15) * NP;
    const float* gp = projs + (9 + ((dgs >> 4) & 15)) * NP;
    const float* sp = projs + (17 + (dgs >> 8)) * NP;
#pragma unroll
    for (int j = 0; j < 6; ++j) {
      int n = s * 48 + j * 8;
      f32x4 p0v = *(const f32x4*)(dp + n) + *(const f32x4*)(gp + n) + *(const f32x4*)(sp + n);
      f32x4 p1v = *(const f32x4*)(dp + n + 4) + *(const f32x4*)(gp + n + 4) + *(const f32x4*)(sp + n + 4);
      if (n < 160) {
        u32x4 a8 = *(const u32x4*)(Ar + n);
        u32x4 b8 = *(const u32x4*)(Br + n);
        p0v.x += bf2f(a8.x & 0xffff) + bf2f(b8.x & 0xffff);
        p0v.y += bf2f(a8.x >> 16)    + bf2f(b8.x >> 16);
        p0v.z += bf2f(a8.y & 0xffff) + bf2f(b8.y & 0xffff);
        p0v.w += bf2f(a8.y >> 16)    + bf2f(b8.y >> 16);
        p1v.x += bf2f(a8.z & 0xffff) + bf2f(b8.z & 0xffff);
        p1v.y += bf2f(a8.z >> 16)    + bf2f(b8.z >> 16);
        p1v.z += bf2f(a8.w & 0xffff) + bf2f(b8.w & 0xffff);
        p1v.w += bf2f(a8.w >> 16)    + bf2f(b8.w >> 16);
      }
      u32x4 o;
      o.x = pk2(p0v.x, p0v.y); o.y = pk2(p0v.z, p0v.w);
      o.z = pk2(p1v.x, p1v.y); o.w = pk2(p1v.z, p1v.w);
      *(u32x4*)&sX[r * 200 + n] = o;
    }
  }
  __syncthreads();

  // ---- epilogue 1: h1 = relu(acc + bias), in-place (same (m,n) cell owner)
#pragma unroll
  for (int mi = 0; mi < 4; ++mi)
#pragma unroll
    for (int tl = 0; tl < 3; ++tl) {
      int n = (w * 3 + tl) * 16 + lm;
#pragma unroll
      for (int reg = 0; reg < 4; ++reg) {
        int m = mi * 16 + quad * 4 + reg;
        float v = acc[mi][tl][reg] + bf2f(sX[m * 200 + n]);
        sX[m * 200 + n] = f2bf(fmaxf(v, 0.f));
      }
    }
  __syncthreads();

  // ---- layer 2: h1[64][192] @ W2_t
  f32x4 acc2[4][3];
#pragma unroll
  for (int a = 0; a < 4; ++a)
#pragma unroll
    for (int b = 0; b < 3; ++b) { acc2[a][b].x = 0.f; acc2[a][b].y = 0.f; acc2[a][b].z = 0.f; acc2[a][b].w = 0.f; }
#pragma unroll
  for (int kk = 0; kk < 6; ++kk) {
    bf16x8 af[4];
#pragma unroll
    for (int mi = 0; mi < 4; ++mi)
      af[mi] = __builtin_bit_cast(bf16x8, *(const u32x4*)&sX[(mi * 16 + lm) * 200 + kk * 32 + quad * 8]);
#pragma unroll
    for (int tl = 0; tl < 3; ++tl) {
      int n = (w * 3 + tl) * 16 + lm;
      bf16x8 bfr = __builtin_bit_cast(bf16x8, *(const u32x4*)(W2_t + n * NP + kk * 32 + quad * 8));
#pragma unroll
      for (int mi = 0; mi < 4; ++mi)
        acc2[mi][tl] = __builtin_amdgcn_mfma_f32_16x16x32_bf16(af[mi], bfr, acc2[mi][tl], 0, 0, 0);
    }
  }
  __syncthreads();   // all waves done reading h1 before h2 overwrites

  // ---- epilogue 2: h2 = relu(acc2 + b2) -> same cells
#pragma unroll
  for (int mi = 0; mi < 4; ++mi)
#pragma unroll
    for (int tl = 0; tl < 3; ++tl) {
      int n = (w * 3 + tl) * 16 + lm;
      float bb = (n < 150) ? b2[n] : 0.f;
#pragma unroll
      for (int reg = 0; reg < 4; ++reg) {
        int m = mi * 16 + quad * 4 + reg;
        float v = acc2[mi][tl][reg] + bb;
        sX[m * 200 + n] = f2bf(fmaxf(v, 0.f));
      }
    }
  __syncthreads();

  // ---- layer 3: pairwise = h2 . W3 ; sij = ms_i + ms_j + pairwise + b3
  {
    float sum = 0.f;
#pragma unroll
    for (int j = 0; j < 48; ++j) {
      int n = s * 48 + j;
      if (n < 150) sum += bf2f(sX[r * 200 + n]) * W3[n];
    }
    sum += __shfl_xor(sum, 1);
    sum += __shfl_xor(sum, 2);
    if (s == 0) {
      int p = p0 + r;
      if (p < P) out[p] = msc[sM[r]] + msc[sA[r]] + sum + b3[0];
    }
  }
}

extern "C" void kernel_launch(void* const* d_in, const int* in_sizes, int n_in,
                              void* d_out, int out_size, void* d_ws, size_t ws_size,
                              hipStream_t stream) {
  (void)n_in; (void)out_size;
  const float* g   = (const float*)d_in[0];
  const float* msc = (const float*)d_in[1];
  const float* de  = (const float*)d_in[2];
  const float* ge  = (const float*)d_in[3];
  const float* se  = (const float*)d_in[4];
  const float* W1  = (const float*)d_in[5];
  const float* b1  = (const float*)d_in[6];
  const float* W2  = (const float*)d_in[7];
  const float* b2  = (const float*)d_in[8];
  const float* W3  = (const float*)d_in[9];
  const float* b3  = (const float*)d_in[10];
  const int* mid = (const int*)d_in[11];
  const int* aid = (const int*)d_in[12];
  const int* did = (const int*)d_in[13];
  const int* gid = (const int*)d_in[14];
  const int* sid = (const int*)d_in[15];
  const int N = in_sizes[0] / GI;
  const int P = in_sizes[11];
  float* out = (float*)d_out;

  char* ws = (char*)d_ws;
  size_t off = 0;
  auto alloc = [&](size_t bytes) { char* p = ws + off; off = (off + bytes + 255) & ~(size_t)255; return p; };
  unsigned short* AB     = (unsigned short*)alloc((size_t)N * ABW * 2);
  unsigned short* W1ab_t = (unsigned short*)alloc((size_t)ABW * KP * 2);
  unsigned short* W1c_t  = (unsigned short*)alloc((size_t)NP * KP * 2);
  unsigned short* W2_t   = (unsigned short*)alloc((size_t)NP * NP * 2);
  float* projs           = (float*)alloc((size_t)20 * NP * 4);

  // g_pad (bf16, zero-padded rows of KP) only if ws is big enough
  size_t gpad_bytes = (size_t)N * KP * 2;
  unsigned short* gpad = nullptr;
  if (off + gpad_bytes + 256 <= ws_size)
    gpad = (unsigned short*)alloc(gpad_bytes);

  const int prep_total = ABW * KP + NP * KP + NP * NP + 20 * NP;
  prep_kernel<<<(prep_total + 255) / 256, 256, 0, stream>>>(W1, W2, b1, de, ge, se,
                                                            W1ab_t, W1c_t, W2_t, projs);
  ab_kernel<<<(N + 63) / 64, 256, 0, stream>>>(g, W1ab_t, AB, gpad, N);
  if (gpad)
    pair_kernel<true><<<(P + 63) / 64, 256, 0, stream>>>(g, gpad, msc, AB, W1c_t, W2_t, projs,
                                                         b2, W3, b3, mid, aid, did, gid, sid, out, P);
  else
    pair_kernel<false><<<(P + 63) / 64, 256, 0, stream>>>(g, gpad, msc, AB, W1c_t, W2_t, projs,
                                                          b2, W3, b3, mid, aid, did, gid, sid, out, P);
}